// Round 2
// baseline (417.332 us; speedup 1.0000x reference)
//
#include <hip/hip_runtime.h>

#define VOCAB 50257
#define DM    1024
#define NN    512     // geometry dim n
#define KGEOM 64      // k per batch
#define NB    4       // batch
#define LL    2048    // seq len
#define NKROWS 32768  // N*K rows of W

typedef __attribute__((ext_vector_type(4))) float f32x4;
typedef __attribute__((ext_vector_type(8))) short bf16x8;

__device__ __forceinline__ unsigned short f2bf(float f) {
    unsigned int u = __float_as_uint(f);
    u = u + 0x7FFFu + ((u >> 16) & 1u);   // round-to-nearest-even
    return (unsigned short)(u >> 16);
}

// ---------------------------------------------------------------------------
// Kernel 1: ctx accumulation.  grid = (NB * 64) blocks, 256 threads.
// Each block handles 32 tokens of one batch; each loop iteration reads one
// FULL embedding row coalesced (256 threads * float4 = 4KB = one row).
// ---------------------------------------------------------------------------
__global__ __launch_bounds__(256) void k_ctx(const int* __restrict__ ids,
                                             const float* __restrict__ emb,
                                             float* __restrict__ ctx) {
    const int b  = blockIdx.x >> 6;
    const int ch = blockIdx.x & 63;
    const int t  = threadIdx.x;
    const int base = b * LL + ch * 32;
    float4 s = make_float4(0.f, 0.f, 0.f, 0.f);
#pragma unroll 4
    for (int i = 0; i < 32; ++i) {
        const int row = ids[base + i];
        const float4 v = *reinterpret_cast<const float4*>(emb + (size_t)row * DM + t * 4);
        s.x += v.x; s.y += v.y; s.z += v.z; s.w += v.w;
    }
    float* dst = ctx + b * DM + t * 4;
    atomicAdd(dst + 0, s.x);
    atomicAdd(dst + 1, s.y);
    atomicAdd(dst + 2, s.z);
    atomicAdd(dst + 3, s.w);
}

// ---------------------------------------------------------------------------
// Kernel 2: U = ctx @ W.T + bias, written as bf16 in B^T layout:
//   BT[b*64 + (r&63)][r>>6]  (BT is [256][512] bf16)
// grid = 8192 blocks * 256 threads; one wave per W row, 4 batches per row.
// ---------------------------------------------------------------------------
__global__ __launch_bounds__(256) void k_u(const float* __restrict__ ctx,
                                           const float* __restrict__ W,
                                           const float* __restrict__ bias,
                                           unsigned short* __restrict__ BT) {
    __shared__ float cs[NB * DM];
    const int t = threadIdx.x;
    const float inv = 1.0f / 2048.0f;
#pragma unroll
    for (int i = 0; i < 4; ++i) {
        const int p = i * 256 + t;  // float4 index into ctx (1024 float4 total)
        float4 v = *reinterpret_cast<const float4*>(ctx + p * 4);
        v.x *= inv; v.y *= inv; v.z *= inv; v.w *= inv;
        *reinterpret_cast<float4*>(cs + p * 4) = v;
    }
    __syncthreads();

    const int wid = t >> 6, lane = t & 63;
    const int r = blockIdx.x * 4 + wid;
    const float4* Wr = reinterpret_cast<const float4*>(W + (size_t)r * DM);
    float s0 = 0.f, s1 = 0.f, s2 = 0.f, s3 = 0.f;
#pragma unroll
    for (int rd = 0; rd < 4; ++rd) {
        const float4 w = Wr[rd * 64 + lane];
        const int q = (rd * 64 + lane) * 4;
        const float4 c0 = *reinterpret_cast<const float4*>(cs + 0 * DM + q);
        const float4 c1 = *reinterpret_cast<const float4*>(cs + 1 * DM + q);
        const float4 c2 = *reinterpret_cast<const float4*>(cs + 2 * DM + q);
        const float4 c3 = *reinterpret_cast<const float4*>(cs + 3 * DM + q);
        s0 += w.x * c0.x + w.y * c0.y + w.z * c0.z + w.w * c0.w;
        s1 += w.x * c1.x + w.y * c1.y + w.z * c1.z + w.w * c1.w;
        s2 += w.x * c2.x + w.y * c2.y + w.z * c2.z + w.w * c2.w;
        s3 += w.x * c3.x + w.y * c3.y + w.z * c3.z + w.w * c3.w;
    }
#pragma unroll
    for (int m = 1; m < 64; m <<= 1) {
        s0 += __shfl_xor(s0, m);
        s1 += __shfl_xor(s1, m);
        s2 += __shfl_xor(s2, m);
        s3 += __shfl_xor(s3, m);
    }
    if (lane < 4) {
        float u = (lane == 0) ? s0 : (lane == 1) ? s1 : (lane == 2) ? s2 : s3;
        u += bias[r];
        BT[(lane * 64 + (r & 63)) * NN + (r >> 6)] = f2bf(u);
    }
}

// ---------------------------------------------------------------------------
// Kernel 3: C(V x 256) = geom(V x 512) @ U_all(512 x 256), then
// out[b][v] = sum over the 64 columns of batch b of C^2.
// BM=256, BN=256 (=all), BK=64. 512 threads = 8 waves (2 x 4), wave tile
// 128x64.  Reg-staged f32->bf16 into XOR-swizzled LDS, mfma 16x16x32 bf16.
// ---------------------------------------------------------------------------
__global__ __launch_bounds__(512, 2) void k_gemm(const float* __restrict__ geom,
                                                 const unsigned short* __restrict__ BT,
                                                 float* __restrict__ out) {
    __shared__ __align__(16) unsigned short As[256 * 64];  // [row][k] bf16, swizzled
    __shared__ __align__(16) unsigned short Bs[256 * 64];  // [col][k] bf16, swizzled
    const int t = threadIdx.x;
    const int lane = t & 63;
    const int wid = t >> 6;
    const int wr = wid >> 2;   // 0..1
    const int wc = wid & 3;    // 0..3 == batch index
    const int m0 = blockIdx.x * 256;

    f32x4 acc[8][4];
#pragma unroll
    for (int m = 0; m < 8; ++m)
#pragma unroll
        for (int n = 0; n < 4; ++n) acc[m][n] = (f32x4){0.f, 0.f, 0.f, 0.f};

    const int arow = t >> 4;  // 0..31
    const int acol = t & 15;  // float4 index within 64-col window
    const int brow = t >> 3;  // 0..63
    const int bcol = t & 7;   // 16B chunk within 128B row

    float4 ar[8];
    int4   br4[4];

    auto loadA = [&](int kt) {
        const int kc = kt * 64 + acol * 4;
#pragma unroll
        for (int rd = 0; rd < 8; ++rd) {
            int row = m0 + rd * 32 + arow;
            row = row < VOCAB ? row : VOCAB - 1;
            ar[rd] = *reinterpret_cast<const float4*>(geom + (size_t)row * NN + kc);
        }
    };
    auto loadB = [&](int kt) {
        const int kc = kt * 64 + bcol * 8;  // ushort units
#pragma unroll
        for (int rd = 0; rd < 4; ++rd) {
            const int row = rd * 64 + brow;
            br4[rd] = *reinterpret_cast<const int4*>(BT + row * NN + kc);
        }
    };
    auto storeA = [&]() {
#pragma unroll
        for (int rd = 0; rd < 8; ++rd) {
            const int rl = rd * 32 + arow;
            const int byte = rl * 128 + ((acol * 8) ^ ((rl & 7) << 4));
            const unsigned int lo = (unsigned)f2bf(ar[rd].x) | ((unsigned)f2bf(ar[rd].y) << 16);
            const unsigned int hi = (unsigned)f2bf(ar[rd].z) | ((unsigned)f2bf(ar[rd].w) << 16);
            *reinterpret_cast<uint2*>(reinterpret_cast<char*>(As) + byte) = make_uint2(lo, hi);
        }
    };
    auto storeB = [&]() {
#pragma unroll
        for (int rd = 0; rd < 4; ++rd) {
            const int rl = rd * 64 + brow;
            const int byte = rl * 128 + ((bcol * 16) ^ ((rl & 7) << 4));
            *reinterpret_cast<int4*>(reinterpret_cast<char*>(Bs) + byte) = br4[rd];
        }
    };

    loadA(0);
    loadB(0);
    const char* Ab = reinterpret_cast<const char*>(As);
    const char* Bb = reinterpret_cast<const char*>(Bs);

    for (int kt = 0; kt < 8; ++kt) {
        storeA();
        storeB();
        __syncthreads();
        if (kt < 7) { loadA(kt + 1); loadB(kt + 1); }  // T14: issue early, hide under MFMA
#pragma unroll
        for (int kk = 0; kk < 2; ++kk) {
            bf16x8 af[8], bfr[4];
            const int cb = kk * 64 + (lane >> 4) * 16;  // byte col of 16B fragment
#pragma unroll
            for (int n = 0; n < 4; ++n) {
                const int col = wc * 64 + n * 16 + (lane & 15);
                bfr[n] = *reinterpret_cast<const bf16x8*>(Bb + col * 128 + (cb ^ ((col & 7) << 4)));
            }
#pragma unroll
            for (int m = 0; m < 8; ++m) {
                const int row = wr * 128 + m * 16 + (lane & 15);
                af[m] = *reinterpret_cast<const bf16x8*>(Ab + row * 128 + (cb ^ ((row & 7) << 4)));
            }
#pragma unroll
            for (int m = 0; m < 8; ++m)
#pragma unroll
                for (int n = 0; n < 4; ++n)
                    acc[m][n] = __builtin_amdgcn_mfma_f32_16x16x32_bf16(af[m], bfr[n], acc[m][n], 0, 0, 0);
        }
        __syncthreads();
    }

    // Epilogue: out[b=wc][v] = sum_j C[v][wc*64+j]^2
    // C/D layout: col = lane&15, row = (lane>>4)*4 + reg
#pragma unroll
    for (int m = 0; m < 8; ++m) {
#pragma unroll
        for (int q = 0; q < 4; ++q) {
            float v = 0.f;
#pragma unroll
            for (int n = 0; n < 4; ++n) {
                const float c = acc[m][n][q];
                v += c * c;
            }
            v += __shfl_xor(v, 1);
            v += __shfl_xor(v, 2);
            v += __shfl_xor(v, 4);
            v += __shfl_xor(v, 8);
            if ((lane & 15) == 0) {
                const int row = m0 + wr * 128 + m * 16 + (lane >> 4) * 4 + q;
                if (row < VOCAB) out[wc * VOCAB + row] = v;
            }
        }
    }
}

// ---------------------------------------------------------------------------
extern "C" void kernel_launch(void* const* d_in, const int* in_sizes, int n_in,
                              void* d_out, int out_size, void* d_ws, size_t ws_size,
                              hipStream_t stream) {
    const int*   ids  = (const int*)d_in[0];
    const float* emb  = (const float*)d_in[1];
    const float* W    = (const float*)d_in[2];
    const float* bias = (const float*)d_in[3];
    const float* geom = (const float*)d_in[4];
    float* out = (float*)d_out;

    float* ctx = (float*)d_ws;                                         // 4096 f32 = 16KB
    unsigned short* BT = (unsigned short*)((char*)d_ws + 16384);       // 256*512 bf16 = 256KB

    hipMemsetAsync(d_ws, 0, 16384, stream);  // zero ctx accumulators (capture-safe)

    k_ctx<<<dim3(NB * 64), dim3(256), 0, stream>>>(ids, emb, ctx);
    k_u<<<dim3(NKROWS / 4), dim3(256), 0, stream>>>(ctx, W, bias, BT);

    const int mblocks = (VOCAB + 255) / 256;  // 197
    k_gemm<<<dim3(mblocks), dim3(512), 0, stream>>>(geom, BT, out);
}